// Round 15
// baseline (167.541 us; speedup 1.0000x reference)
//
#include <hip/hip_runtime.h>
#include <math.h>

// ---------------------------------------------------------------------------
// TMCAM, R14: R13's P4 wave-balance made race-proof.
// R13 post-mortem: post-timing divergence (0.54) -- scheduling-dependent
// flake; only delta vs passing R12 was the P4 remap relying on same-thread
// RAW across P4a->P4b with no barrier. R14: explicit __syncthreads between
// P4a and P4b (handoff correct under ANY mapping) + o-fastest unit map
// (o = u%288, seg = u/288): consecutive lanes same pixel-segment -> sIdx
// branch stays wave-uniform, U writes lane-contiguous. Balance unchanged
// (worst 12 px-iters at l1 vs 18 in R12).
// Ledger: grid.sync banned (R10, ~80us/sync); fused-up2 staging banned (R6);
// P4 full unroll banned (R2/R7 spill); small tiles banned (R9); tile config
// l3 TS=1 / l2 TS=2 / l1 TS=3 (R9-confirmed).
// ---------------------------------------------------------------------------

template<int D, int TS, int H, int W, bool HA>
__global__ __launch_bounds__(256, 4)
void agg_tile(const float* __restrict__ feats,   // (32, 3, H, W)
              const float* __restrict__ add,     // (3, 32, H, W) or null
              const float* __restrict__ agg_w,   // (4)
              const float* __restrict__ agg_b,   // (1)
              const float* __restrict__ wp_w,    // (288, 64) row-major
              const float* __restrict__ wp_b,    // (288)
              float* __restrict__ out)           // (3, 32, H, W)
{
    constexpr int PD = D / 2;
    constexpr int M  = PD + 1;            // stage margin (disp + 3x3 unfold)
    constexpr int R  = TS + 2 * M;        // sA region edge
    constexpr int S  = TS + 2;            // sC region edge
    constexpr int S2 = S * S;
    constexpr int D2 = D * D;
    constexpr int NP = TS * TS;
    constexpr int NX = S2 * D2;
    constexpr int NSIM = NP * D2;
    constexpr int CS = 36;                // padded per-pos float stride
    constexpr int USZ = (NP * 288 > NX + NSIM) ? NP * 288 : NX + NSIM;
    constexpr int TPW = W / TS;
    constexpr int NPA = R * R;
    constexpr int GA  = 256 / NPA;        // channel groups for sA staging
    constexpr int NPS = S * S;
    constexpr int GS  = 256 / NPS;
    constexpr int PPU  = (NP == 9) ? 3 : (NP == 4) ? 2 : 1;  // pixels per unit
    constexpr int NSEG = NP / PPU;        // segments per o
    constexpr int NU   = 288 * NSEG;      // total P4 work units

    __shared__ float sA[NPA * CS];        // feat_tm1 (+add), [pos][c]
    __shared__ float sC[NPS * CS];        // feat_t center (+add), [pos][c]
    __shared__ float t2[NPA];             // sum_c sA^2 per pos
    __shared__ float s2[NPS];             // sum_c sC^2 per pos
    __shared__ float U[USZ];              // X | sSim, then partial/final prod
    __shared__ int   sIdx[NP * 4];        // top-4 sA offsets (pre-scaled) or -1

    float* Xarr = U;                      // NX entries, [u*D2+dd]
    float* sSim = U + NX;                 // NSIM entries

    const int tid  = threadIdx.x;
    const int tile = blockIdx.x;
    const int t    = blockIdx.y;
    const int y0 = (tile / TPW) * TS;
    const int x0 = (tile % TPW) * TS;

    const float* addT = HA ? (add + (size_t)t * 32 * H * W) : nullptr;

    // ---- P0: stage sA (frame t + add) / sC (frame 1 + add); one div per
    //      thread, channel loop is pure pointer increments ----
    if (tid < NPA * GA) {
        const int pos = tid % NPA;
        const int cb  = tid / NPA;
        const int ry = pos / R, rx = pos % R;
        const int yy = y0 - M + ry, xx = x0 - M + rx;
        float* dst = sA + pos * CS;
        if (yy >= 0 && yy < H && xx >= 0 && xx < W) {
            const float* sF = feats + (((size_t)cb * 3 + t) * H + yy) * W + xx;
            const float* sD = HA ? (addT + ((size_t)cb * H + yy) * W + xx) : nullptr;
            #pragma unroll 1
            for (int c = cb; c < 32; c += GA) {
                float v = *sF; sF += GA * 3 * H * W;
                if (HA) { v += *sD; sD += GA * H * W; }
                dst[c] = v;
            }
        } else {
            #pragma unroll 1
            for (int c = cb; c < 32; c += GA) dst[c] = 0.f;
        }
    }
    if (tid < NPS * GS) {
        const int pos = tid % NPS;
        const int cb  = tid / NPS;
        const int ry = pos / S, rx = pos % S;
        const int yy = y0 - 1 + ry, xx = x0 - 1 + rx;
        float* dst = sC + pos * CS;
        if (yy >= 0 && yy < H && xx >= 0 && xx < W) {
            const float* sF = feats + (((size_t)cb * 3 + 1) * H + yy) * W + xx;
            const float* sD = HA ? (addT + ((size_t)cb * H + yy) * W + xx) : nullptr;
            #pragma unroll 1
            for (int c = cb; c < 32; c += GS) {
                float v = *sF; sF += GS * 3 * H * W;
                if (HA) { v += *sD; sD += GS * H * W; }
                dst[c] = v;
            }
        } else {
            #pragma unroll 1
            for (int c = cb; c < 32; c += GS) dst[c] = 0.f;
        }
    }
    __syncthreads();

    // ---- P1: X (thread = (u,di), sC row cached in regs, D indep dj dots),
    //          t2, s2 (float4 partial chains) ----
    if (tid < S2 * D) {
        const int u  = tid / D;
        const int di = tid - u * D;
        const int uy = u / S, ux = u - uy * S;
        float4 cv[8];
        const float4* c4 = (const float4*)(sC + u * CS);
        #pragma unroll
        for (int i = 0; i < 8; ++i) cv[i] = c4[i];
        const float* arow = sA + ((uy + di) * R + ux) * CS;
        float* xrow = Xarr + u * D2 + di * D;
        #pragma unroll
        for (int dj = 0; dj < D; ++dj) {
            const float4* a4 = (const float4*)(arow + dj * CS);
            float s = 0.f;
            #pragma unroll
            for (int i = 0; i < 8; ++i) {
                float4 av = a4[i];
                s += cv[i].x * av.x + cv[i].y * av.y + cv[i].z * av.z + cv[i].w * av.w;
            }
            xrow[dj] = s;
        }
    }
    for (int e = tid; e < NPA; e += 256) {
        const float4* a4 = (const float4*)(sA + e * CS);
        float4 s4 = make_float4(0.f, 0.f, 0.f, 0.f);
        #pragma unroll
        for (int cc = 0; cc < 8; ++cc) {
            float4 v = a4[cc];
            s4.x += v.x * v.x; s4.y += v.y * v.y;
            s4.z += v.z * v.z; s4.w += v.w * v.w;
        }
        t2[e] = (s4.x + s4.y) + (s4.z + s4.w);
    }
    for (int e = tid; e < NPS; e += 256) {
        const float4* c4 = (const float4*)(sC + e * CS);
        float4 s4 = make_float4(0.f, 0.f, 0.f, 0.f);
        #pragma unroll
        for (int cc = 0; cc < 8; ++cc) {
            float4 v = c4[cc];
            s4.x += v.x * v.x; s4.y += v.y * v.y;
            s4.z += v.z * v.z; s4.w += v.w * v.w;
        }
        s2[e] = (s4.x + s4.y) + (s4.z + s4.w);
    }
    __syncthreads();

    // ---- P2: sims (mask out-of-image displaced centers to exactly 0) ----
    for (int e = tid; e < NSIM; e += 256) {
        int p = e / D2, dd = e - p * D2;
        int py = p / TS, px = p - py * TS;
        int di = dd / D, dj = dd - di * D;
        int Yc = y0 + py + di - PD, Xc = x0 + px + dj - PD;
        float sim = 0.f;
        if (Yc >= 0 && Yc < H && Xc >= 0 && Xc < W) {
            float dot = 0.f, n2 = 0.f, nf = 0.f;
            #pragma unroll
            for (int qi = 0; qi < 3; ++qi)
            #pragma unroll
            for (int qj = 0; qj < 3; ++qj) {
                dot += Xarr[((py + qi) * S + (px + qj)) * D2 + dd];
                n2  += t2[(py + qi + di) * R + (px + qj + dj)];
                nf  += s2[(py + qi) * S + (px + qj)];
            }
            sim = dot / fmaxf(sqrtf(nf), 1e-12f) / fmaxf(sqrtf(n2), 1e-12f);
        }
        sSim[e] = sim;
    }
    __syncthreads();

    // ---- P3: per-pixel top-4 (strict-insert == stable ties, lax.top_k);
    //      store pre-scaled sA offsets ----
    if (tid < NP) {
        float v0 = -3.0e38f, v1 = -3.0e38f, v2 = -3.0e38f, v3 = -3.0e38f;
        int   i0 = 0, i1 = 0, i2 = 0, i3 = 0;
        const float* row = sSim + tid * D2;
        for (int dd = 0; dd < D2; ++dd) {
            float v = row[dd];
            if (v > v0)      { v3=v2;i3=i2; v2=v1;i2=i1; v1=v0;i1=i0; v0=v;i0=dd; }
            else if (v > v1) { v3=v2;i3=i2; v2=v1;i2=i1; v1=v;i1=dd; }
            else if (v > v2) { v3=v2;i3=i2; v2=v;i2=dd; }
            else if (v > v3) { v3=v;i3=dd; }
        }
        int py = tid / TS, px = tid - (tid / TS) * TS;
        int ids[4] = {i0, i1, i2, i3};
        #pragma unroll
        for (int k = 0; k < 4; ++k) {
            int dd = ids[k];
            int di = dd / D, dj = dd - di * D;
            int Yc = y0 + py + di - PD, Xc = x0 + px + dj - PD;
            sIdx[tid * 4 + k] = (Yc >= 0 && Yc < H && Xc >= 0 && Xc < W)
                              ? (di * R + dj) * CS : -1;
        }
    }
    __syncthreads();

    // ---- P4a: partial wm, feat_t half. Unit = (seg, o), o fastest:
    //      consecutive lanes -> same pixel segment (uniform sIdx later),
    //      contiguous U writes. NU units over 256 threads (balanced). ----
    const float4* wp4 = (const float4*)wp_w;
    #pragma unroll 1
    for (int u = tid; u < NU; u += 256) {
        const int o   = u % 288;
        const int p0  = (u / 288) * PPU;
        float4 w[8];
        #pragma unroll
        for (int i = 0; i < 8; ++i) w[i] = wp4[o * 16 + i];
        const float wb = wp_b[o];
        #pragma unroll 1
        for (int p = p0; p < p0 + PPU; ++p) {
            const int py = p / TS, px = p - (p / TS) * TS;
            const float4* pv4 = (const float4*)(sC + ((py + 1) * S + (px + 1) ) * CS);
            float4 a4 = make_float4(wb, 0.f, 0.f, 0.f);
            #pragma unroll
            for (int i = 0; i < 8; ++i) {
                float4 pv = pv4[i];
                a4.x += w[i].x * pv.x; a4.y += w[i].y * pv.y;
                a4.z += w[i].z * pv.z; a4.w += w[i].w * pv.w;
            }
            U[p * 288 + o] = (a4.x + a4.y) + (a4.z + a4.w);
        }
    }
    __syncthreads();   // race-proof handoff: P4b may read any U entry

    // ---- P4b: finish wm (feat_tm1 half) + aggd gather + multiply ----
    const float aw0 = agg_w[0], aw1 = agg_w[1], aw2 = agg_w[2], aw3 = agg_w[3];
    const float ab  = agg_b[0];
    #pragma unroll 1
    for (int u = tid; u < NU; u += 256) {
        const int o   = u % 288;
        const int p0  = (u / 288) * PPU;
        const int c = o / 9, q = o - (o / 9) * 9;
        const int qi = q / 3, qj = q - (q / 3) * 3;
        const int qoff = (qi * R + qj) * CS + c;   // gather base (per o)
        float4 w[8];
        #pragma unroll
        for (int i = 0; i < 8; ++i) w[i] = wp4[o * 16 + 8 + i];
        #pragma unroll 1
        for (int p = p0; p < p0 + PPU; ++p) {
            const int py = p / TS, px = p - (p / TS) * TS;
            const float4* pv4 = (const float4*)(sA + ((py + M) * R + (px + M)) * CS);
            float4 a4 = make_float4(U[p * 288 + o], 0.f, 0.f, 0.f);
            #pragma unroll
            for (int i = 0; i < 8; ++i) {
                float4 pv = pv4[i];
                a4.x += w[i].x * pv.x; a4.y += w[i].y * pv.y;
                a4.z += w[i].z * pv.z; a4.w += w[i].w * pv.w;
            }
            const float acc = (a4.x + a4.y) + (a4.z + a4.w);
            const int gbase = (py * R + px) * CS + qoff;     // + soff -> addr
            float aggd = ab;
            #pragma unroll
            for (int k = 0; k < 4; ++k) {
                int soff = sIdx[p * 4 + k];       // near-uniform branch
                if (soff >= 0) {
                    float val = sA[gbase + soff];
                    float aw = (k == 0) ? aw0 : (k == 1) ? aw1 : (k == 2) ? aw2 : aw3;
                    aggd += aw * val;
                }
            }
            U[p * 288 + o] = aggd * acc;
        }
    }
    __syncthreads();

    // ---- P5: reduce over the 9 patch positions, store ----
    for (int e = tid; e < 32 * NP; e += 256) {
        int c = e / NP, p = e - (e / NP) * NP;
        int py = p / TS, px = p - (p / TS) * TS;
        float s = 0.f;
        const float* up = U + p * 288 + c * 9;
        #pragma unroll
        for (int q = 0; q < 9; ++q) s += up[q];
        out[((t * 32 + c) * H + (y0 + py)) * W + (x0 + px)] = s;
    }
}

// jax.image.resize(method='linear') 2x: half-pixel centers, edge weights renorm
// to pure clamp. even o=2m: 0.25*x[m-1]+0.75*x[m]; odd o=2m+1: 0.75*x[m]+0.25*x[m+1].
__global__ void up2_kernel(const float* __restrict__ in, float* __restrict__ out,
                           int C, int h, int w)
{
    int idx = blockIdx.x * blockDim.x + threadIdx.x;
    int H = 2 * h, W = 2 * w;
    int total = C * H * W;
    if (idx >= total) return;
    int ox = idx % W;
    int oy = (idx / W) % H;
    int c  = idx / (W * H);

    int my = oy >> 1, mx = ox >> 1;
    int y0, y1, x0, x1;
    float wy0, wy1, wx0, wx1;
    if ((oy & 1) == 0) { y0 = max(my - 1, 0); y1 = my; wy0 = 0.25f; wy1 = 0.75f; }
    else               { y0 = my; y1 = min(my + 1, h - 1); wy0 = 0.75f; wy1 = 0.25f; }
    if ((ox & 1) == 0) { x0 = max(mx - 1, 0); x1 = mx; wx0 = 0.25f; wx1 = 0.75f; }
    else               { x0 = mx; x1 = min(mx + 1, w - 1); wx0 = 0.75f; wx1 = 0.25f; }

    const float* pc = in + (size_t)c * h * w;
    float v = wy0 * (wx0 * pc[y0 * w + x0] + wx1 * pc[y0 * w + x1])
            + wy1 * (wx0 * pc[y1 * w + x0] + wx1 * pc[y1 * w + x1]);
    out[idx] = v;
}

// final: out128[o,y,x] = up_b[o] + sum_i up_w[o,i]*a1cat[i,y,x]; pixel_shuffle r=2.
// o from blockIdx.y -> weight reads scalar, a1 reads coalesced.
// 4 scalar partial accumulators = 4 independent FMA chains.
__global__ __launch_bounds__(256)
void final_kernel(const float* __restrict__ a1,   // (96, 48, 48)
                  const float* __restrict__ up_w, // (128, 96)
                  const float* __restrict__ up_b, // (128)
                  float* __restrict__ out)        // (32, 96, 96)
{
    const int pix = blockIdx.x * 256 + threadIdx.x;   // 0..2303
    const int o   = blockIdx.y;                       // 0..127 (uniform)
    const int x = pix % 48, y = pix / 48;

    const float* w = up_w + o * 96;
    float a0 = up_b[o], a1p = 0.f, a2p = 0.f, a3p = 0.f;
    #pragma unroll 1
    for (int i = 0; i < 96; i += 4) {
        a0  += w[i]     * a1[(i)     * 2304 + pix];
        a1p += w[i + 1] * a1[(i + 1) * 2304 + pix];
        a2p += w[i + 2] * a1[(i + 2) * 2304 + pix];
        a3p += w[i + 3] * a1[(i + 3) * 2304 + pix];
    }
    float acc = (a0 + a1p) + (a2p + a3p);

    int co = o >> 2, ry = (o >> 1) & 1, rx = o & 1;
    out[((co * 96 + 2 * y + ry) * 96) + 2 * x + rx] = acc;
}

extern "C" void kernel_launch(void* const* d_in, const int* in_sizes, int n_in,
                              void* d_out, int out_size, void* d_ws, size_t ws_size,
                              hipStream_t stream)
{
    const float* feats_l1 = (const float*)d_in[0];
    const float* feats_l2 = (const float*)d_in[1];
    const float* feats_l3 = (const float*)d_in[2];
    const float* agg_l3_w = (const float*)d_in[3];
    const float* agg_l3_b = (const float*)d_in[4];
    const float* wp_l3_w  = (const float*)d_in[5];
    const float* wp_l3_b  = (const float*)d_in[6];
    const float* agg_l2_w = (const float*)d_in[7];
    const float* agg_l2_b = (const float*)d_in[8];
    const float* wp_l2_w  = (const float*)d_in[9];
    const float* wp_l2_b  = (const float*)d_in[10];
    const float* agg_l1_w = (const float*)d_in[11];
    const float* agg_l1_b = (const float*)d_in[12];
    const float* wp_l1_w  = (const float*)d_in[13];
    const float* wp_l1_b  = (const float*)d_in[14];
    const float* up_w     = (const float*)d_in[15];
    const float* up_b     = (const float*)d_in[16];
    float* out = (float*)d_out;

    float* ws   = (float*)d_ws;
    float* agg3 = ws;                  // 3*32*12*12  = 13824
    float* a3up = agg3 + 13824;        // 3*32*24*24  = 55296
    float* agg2 = a3up + 55296;        // 3*32*24*24  = 55296
    float* a2up = agg2 + 55296;        // 3*32*48*48  = 221184
    float* a1   = a2up + 221184;       // 3*32*48*48  = 221184

    // level 3 (12x12, d=3), 1x1 tiles -> 144 x 3 = 432 blocks, no add
    agg_tile<3, 1, 12, 12, false><<<dim3(144, 3), 256, 0, stream>>>(
        feats_l3, nullptr, agg_l3_w, agg_l3_b, wp_l3_w, wp_l3_b, agg3);
    up2_kernel<<<(96 * 24 * 24 + 255) / 256, 256, 0, stream>>>(agg3, a3up, 96, 12, 12);

    // level 2 (24x24, d=5), 2x2 tiles -> 144 x 3 = 432 blocks
    agg_tile<5, 2, 24, 24, true><<<dim3(144, 3), 256, 0, stream>>>(
        feats_l2, a3up, agg_l2_w, agg_l2_b, wp_l2_w, wp_l2_b, agg2);
    up2_kernel<<<(96 * 48 * 48 + 255) / 256, 256, 0, stream>>>(agg2, a2up, 96, 24, 24);

    // level 1 (48x48, d=7), 3x3 tiles -> 256 x 3 = 768 blocks (= 3/CU)
    agg_tile<7, 3, 48, 48, true><<<dim3(256, 3), 256, 0, stream>>>(
        feats_l1, a2up, agg_l1_w, agg_l1_b, wp_l1_w, wp_l1_b, a1);

    // final projection + pixel shuffle (o uniform per block -> scalar weights)
    final_kernel<<<dim3(9, 128), 256, 0, stream>>>(a1, up_w, up_b, out);
}

// Round 16
// 159.352 us; speedup vs baseline: 1.0514x; 1.0514x over previous
//
#include <hip/hip_runtime.h>
#include <math.h>

// ---------------------------------------------------------------------------
// TMCAM, R15 = R12 verbatim (champion restore, 160.0 us).
// R13 post-mortem: P4 rebalance w/o barrier -> post-timing divergence flake.
// R14 post-mortem: race-proofed rebalance -> +7.5us (per-unit weight-row
// reloads + extra barrier eat the balance gain). P4-remap branch closed.
// R12 content: R8 structure + FMA-chain ILP (float4 accumulators = 4 indep
// chains) in P4a/P4b/final. Tile config l3 TS=1 / l2 TS=2 / l1 TS=3 (R9).
// Ledger of banned moves (all measured): grid.sync (R10, ~80us each);
// fused-up2-in-staging (R6); P4 full unroll (R2/R7 spill); small tiles (R9);
// P4 unit remap (R13 unsafe / R14 slower).
// ---------------------------------------------------------------------------

template<int D, int TS, int H, int W, bool HA>
__global__ __launch_bounds__(256, 4)
void agg_tile(const float* __restrict__ feats,   // (32, 3, H, W)
              const float* __restrict__ add,     // (3, 32, H, W) or null
              const float* __restrict__ agg_w,   // (4)
              const float* __restrict__ agg_b,   // (1)
              const float* __restrict__ wp_w,    // (288, 64) row-major
              const float* __restrict__ wp_b,    // (288)
              float* __restrict__ out)           // (3, 32, H, W)
{
    constexpr int PD = D / 2;
    constexpr int M  = PD + 1;            // stage margin (disp + 3x3 unfold)
    constexpr int R  = TS + 2 * M;        // sA region edge
    constexpr int S  = TS + 2;            // sC region edge
    constexpr int S2 = S * S;
    constexpr int D2 = D * D;
    constexpr int NP = TS * TS;
    constexpr int NX = S2 * D2;
    constexpr int NSIM = NP * D2;
    constexpr int CS = 36;                // padded per-pos float stride
    constexpr int USZ = (NP * 288 > NX + NSIM) ? NP * 288 : NX + NSIM;
    constexpr int TPW = W / TS;
    constexpr int NPA = R * R;
    constexpr int GA  = 256 / NPA;        // channel groups for sA staging
    constexpr int NPS = S * S;
    constexpr int GS  = 256 / NPS;

    __shared__ float sA[NPA * CS];        // feat_tm1 (+add), [pos][c]
    __shared__ float sC[NPS * CS];        // feat_t center (+add), [pos][c]
    __shared__ float t2[NPA];             // sum_c sA^2 per pos
    __shared__ float s2[NPS];             // sum_c sC^2 per pos
    __shared__ float U[USZ];              // X | sSim, then partial/final prod
    __shared__ int   sIdx[NP * 4];        // top-4 sA offsets (pre-scaled) or -1

    float* Xarr = U;                      // NX entries, [u*D2+dd]
    float* sSim = U + NX;                 // NSIM entries

    const int tid  = threadIdx.x;
    const int tile = blockIdx.x;
    const int t    = blockIdx.y;
    const int y0 = (tile / TPW) * TS;
    const int x0 = (tile % TPW) * TS;

    const float* addT = HA ? (add + (size_t)t * 32 * H * W) : nullptr;

    // ---- P0: stage sA (frame t + add) / sC (frame 1 + add); one div per
    //      thread, channel loop is pure pointer increments ----
    if (tid < NPA * GA) {
        const int pos = tid % NPA;
        const int cb  = tid / NPA;
        const int ry = pos / R, rx = pos % R;
        const int yy = y0 - M + ry, xx = x0 - M + rx;
        float* dst = sA + pos * CS;
        if (yy >= 0 && yy < H && xx >= 0 && xx < W) {
            const float* sF = feats + (((size_t)cb * 3 + t) * H + yy) * W + xx;
            const float* sD = HA ? (addT + ((size_t)cb * H + yy) * W + xx) : nullptr;
            #pragma unroll 1
            for (int c = cb; c < 32; c += GA) {
                float v = *sF; sF += GA * 3 * H * W;
                if (HA) { v += *sD; sD += GA * H * W; }
                dst[c] = v;
            }
        } else {
            #pragma unroll 1
            for (int c = cb; c < 32; c += GA) dst[c] = 0.f;
        }
    }
    if (tid < NPS * GS) {
        const int pos = tid % NPS;
        const int cb  = tid / NPS;
        const int ry = pos / S, rx = pos % S;
        const int yy = y0 - 1 + ry, xx = x0 - 1 + rx;
        float* dst = sC + pos * CS;
        if (yy >= 0 && yy < H && xx >= 0 && xx < W) {
            const float* sF = feats + (((size_t)cb * 3 + 1) * H + yy) * W + xx;
            const float* sD = HA ? (addT + ((size_t)cb * H + yy) * W + xx) : nullptr;
            #pragma unroll 1
            for (int c = cb; c < 32; c += GS) {
                float v = *sF; sF += GS * 3 * H * W;
                if (HA) { v += *sD; sD += GS * H * W; }
                dst[c] = v;
            }
        } else {
            #pragma unroll 1
            for (int c = cb; c < 32; c += GS) dst[c] = 0.f;
        }
    }
    __syncthreads();

    // ---- P1: X (thread = (u,di), sC row cached in regs, D indep dj dots
    //      -> cross-dj ILP already), t2, s2 ----
    if (tid < S2 * D) {
        const int u  = tid / D;
        const int di = tid - u * D;
        const int uy = u / S, ux = u - uy * S;
        float4 cv[8];
        const float4* c4 = (const float4*)(sC + u * CS);
        #pragma unroll
        for (int i = 0; i < 8; ++i) cv[i] = c4[i];
        const float* arow = sA + ((uy + di) * R + ux) * CS;
        float* xrow = Xarr + u * D2 + di * D;
        #pragma unroll
        for (int dj = 0; dj < D; ++dj) {
            const float4* a4 = (const float4*)(arow + dj * CS);
            float s = 0.f;
            #pragma unroll
            for (int i = 0; i < 8; ++i) {
                float4 av = a4[i];
                s += cv[i].x * av.x + cv[i].y * av.y + cv[i].z * av.z + cv[i].w * av.w;
            }
            xrow[dj] = s;
        }
    }
    for (int e = tid; e < NPA; e += 256) {
        const float4* a4 = (const float4*)(sA + e * CS);
        float4 s4 = make_float4(0.f, 0.f, 0.f, 0.f);
        #pragma unroll
        for (int cc = 0; cc < 8; ++cc) {
            float4 v = a4[cc];
            s4.x += v.x * v.x; s4.y += v.y * v.y;
            s4.z += v.z * v.z; s4.w += v.w * v.w;
        }
        t2[e] = (s4.x + s4.y) + (s4.z + s4.w);
    }
    for (int e = tid; e < NPS; e += 256) {
        const float4* c4 = (const float4*)(sC + e * CS);
        float4 s4 = make_float4(0.f, 0.f, 0.f, 0.f);
        #pragma unroll
        for (int cc = 0; cc < 8; ++cc) {
            float4 v = c4[cc];
            s4.x += v.x * v.x; s4.y += v.y * v.y;
            s4.z += v.z * v.z; s4.w += v.w * v.w;
        }
        s2[e] = (s4.x + s4.y) + (s4.z + s4.w);
    }
    __syncthreads();

    // ---- P2: sims (mask out-of-image displaced centers to exactly 0) ----
    for (int e = tid; e < NSIM; e += 256) {
        int p = e / D2, dd = e - p * D2;
        int py = p / TS, px = p - py * TS;
        int di = dd / D, dj = dd - di * D;
        int Yc = y0 + py + di - PD, Xc = x0 + px + dj - PD;
        float sim = 0.f;
        if (Yc >= 0 && Yc < H && Xc >= 0 && Xc < W) {
            float dot = 0.f, n2 = 0.f, nf = 0.f;
            #pragma unroll
            for (int qi = 0; qi < 3; ++qi)
            #pragma unroll
            for (int qj = 0; qj < 3; ++qj) {
                dot += Xarr[((py + qi) * S + (px + qj)) * D2 + dd];
                n2  += t2[(py + qi + di) * R + (px + qj + dj)];
                nf  += s2[(py + qi) * S + (px + qj)];
            }
            sim = dot / fmaxf(sqrtf(nf), 1e-12f) / fmaxf(sqrtf(n2), 1e-12f);
        }
        sSim[e] = sim;
    }
    __syncthreads();

    // ---- P3: per-pixel top-4 (strict-insert == stable ties, lax.top_k);
    //      store pre-scaled sA offsets ----
    if (tid < NP) {
        float v0 = -3.0e38f, v1 = -3.0e38f, v2 = -3.0e38f, v3 = -3.0e38f;
        int   i0 = 0, i1 = 0, i2 = 0, i3 = 0;
        const float* row = sSim + tid * D2;
        for (int dd = 0; dd < D2; ++dd) {
            float v = row[dd];
            if (v > v0)      { v3=v2;i3=i2; v2=v1;i2=i1; v1=v0;i1=i0; v0=v;i0=dd; }
            else if (v > v1) { v3=v2;i3=i2; v2=v1;i2=i1; v1=v;i1=dd; }
            else if (v > v2) { v3=v2;i3=i2; v2=v;i2=dd; }
            else if (v > v3) { v3=v;i3=dd; }
        }
        int py = tid / TS, px = tid - (tid / TS) * TS;
        int ids[4] = {i0, i1, i2, i3};
        #pragma unroll
        for (int k = 0; k < 4; ++k) {
            int dd = ids[k];
            int di = dd / D, dj = dd - di * D;
            int Yc = y0 + py + di - PD, Xc = x0 + px + dj - PD;
            sIdx[tid * 4 + k] = (Yc >= 0 && Yc < H && Xc >= 0 && Xc < W)
                              ? (di * R + dj) * CS : -1;
        }
    }
    __syncthreads();

    // ---- P4a: partial wm from the feat_t half (w[8] regs; pixel loop
    //      unroll-1 with manual py/px; float4 acc = 4 indep FMA chains) ----
    const float4* wp4 = (const float4*)wp_w;
    for (int o = tid; o < 288; o += 256) {
        float4 w[8];
        #pragma unroll
        for (int i = 0; i < 8; ++i) w[i] = wp4[o * 16 + i];
        const float wb = wp_b[o];
        int py = 0, px = 0;
        #pragma unroll 1
        for (int p = 0; p < NP; ++p) {
            const float4* pv4 = (const float4*)(sC + ((py + 1) * S + (px + 1)) * CS);
            float4 a4 = make_float4(wb, 0.f, 0.f, 0.f);
            #pragma unroll
            for (int i = 0; i < 8; ++i) {
                float4 pv = pv4[i];
                a4.x += w[i].x * pv.x; a4.y += w[i].y * pv.y;
                a4.z += w[i].z * pv.z; a4.w += w[i].w * pv.w;
            }
            U[p * 288 + o] = (a4.x + a4.y) + (a4.z + a4.w);
            if (++px == TS) { px = 0; ++py; }
        }
    }
    // ---- P4b: finish wm with feat_tm1 half, aggd gather, multiply.
    //      Same thread touches same U entries -> no barrier needed. ----
    const float aw0 = agg_w[0], aw1 = agg_w[1], aw2 = agg_w[2], aw3 = agg_w[3];
    const float ab  = agg_b[0];
    for (int o = tid; o < 288; o += 256) {
        const int c = o / 9, q = o - (o / 9) * 9;
        const int qi = q / 3, qj = q - (q / 3) * 3;
        const int qoff = (qi * R + qj) * CS + c;   // gather base (per o)
        float4 w[8];
        #pragma unroll
        for (int i = 0; i < 8; ++i) w[i] = wp4[o * 16 + 8 + i];
        int py = 0, px = 0;
        #pragma unroll 1
        for (int p = 0; p < NP; ++p) {
            const float4* pv4 = (const float4*)(sA + ((py + M) * R + (px + M)) * CS);
            float4 a4 = make_float4(U[p * 288 + o], 0.f, 0.f, 0.f);
            #pragma unroll
            for (int i = 0; i < 8; ++i) {
                float4 pv = pv4[i];
                a4.x += w[i].x * pv.x; a4.y += w[i].y * pv.y;
                a4.z += w[i].z * pv.z; a4.w += w[i].w * pv.w;
            }
            const float acc = (a4.x + a4.y) + (a4.z + a4.w);
            const int gbase = (py * R + px) * CS + qoff;     // + soff -> addr
            float aggd = ab;
            #pragma unroll
            for (int k = 0; k < 4; ++k) {
                int soff = sIdx[p * 4 + k];       // wave-uniform branch
                if (soff >= 0) {
                    float val = sA[gbase + soff];
                    float aw = (k == 0) ? aw0 : (k == 1) ? aw1 : (k == 2) ? aw2 : aw3;
                    aggd += aw * val;
                }
            }
            U[p * 288 + o] = aggd * acc;
            if (++px == TS) { px = 0; ++py; }
        }
    }
    __syncthreads();

    // ---- P5: reduce over the 9 patch positions, store ----
    for (int e = tid; e < 32 * NP; e += 256) {
        int c = e / NP, p = e - (e / NP) * NP;
        int py = p / TS, px = p - (p / TS) * TS;
        float s = 0.f;
        const float* up = U + p * 288 + c * 9;
        #pragma unroll
        for (int q = 0; q < 9; ++q) s += up[q];
        out[((t * 32 + c) * H + (y0 + py)) * W + (x0 + px)] = s;
    }
}

// jax.image.resize(method='linear') 2x: half-pixel centers, edge weights renorm
// to pure clamp. even o=2m: 0.25*x[m-1]+0.75*x[m]; odd o=2m+1: 0.75*x[m]+0.25*x[m+1].
__global__ void up2_kernel(const float* __restrict__ in, float* __restrict__ out,
                           int C, int h, int w)
{
    int idx = blockIdx.x * blockDim.x + threadIdx.x;
    int H = 2 * h, W = 2 * w;
    int total = C * H * W;
    if (idx >= total) return;
    int ox = idx % W;
    int oy = (idx / W) % H;
    int c  = idx / (W * H);

    int my = oy >> 1, mx = ox >> 1;
    int y0, y1, x0, x1;
    float wy0, wy1, wx0, wx1;
    if ((oy & 1) == 0) { y0 = max(my - 1, 0); y1 = my; wy0 = 0.25f; wy1 = 0.75f; }
    else               { y0 = my; y1 = min(my + 1, h - 1); wy0 = 0.75f; wy1 = 0.25f; }
    if ((ox & 1) == 0) { x0 = max(mx - 1, 0); x1 = mx; wx0 = 0.25f; wx1 = 0.75f; }
    else               { x0 = mx; x1 = min(mx + 1, w - 1); wx0 = 0.75f; wx1 = 0.25f; }

    const float* pc = in + (size_t)c * h * w;
    float v = wy0 * (wx0 * pc[y0 * w + x0] + wx1 * pc[y0 * w + x1])
            + wy1 * (wx0 * pc[y1 * w + x0] + wx1 * pc[y1 * w + x1]);
    out[idx] = v;
}

// final: out128[o,y,x] = up_b[o] + sum_i up_w[o,i]*a1cat[i,y,x]; pixel_shuffle r=2.
// o from blockIdx.y -> weight reads scalar, a1 reads coalesced.
// 4 scalar partial accumulators = 4 independent FMA chains.
__global__ __launch_bounds__(256)
void final_kernel(const float* __restrict__ a1,   // (96, 48, 48)
                  const float* __restrict__ up_w, // (128, 96)
                  const float* __restrict__ up_b, // (128)
                  float* __restrict__ out)        // (32, 96, 96)
{
    const int pix = blockIdx.x * 256 + threadIdx.x;   // 0..2303
    const int o   = blockIdx.y;                       // 0..127 (uniform)
    const int x = pix % 48, y = pix / 48;

    const float* w = up_w + o * 96;
    float a0 = up_b[o], a1p = 0.f, a2p = 0.f, a3p = 0.f;
    #pragma unroll 1
    for (int i = 0; i < 96; i += 4) {
        a0  += w[i]     * a1[(i)     * 2304 + pix];
        a1p += w[i + 1] * a1[(i + 1) * 2304 + pix];
        a2p += w[i + 2] * a1[(i + 2) * 2304 + pix];
        a3p += w[i + 3] * a1[(i + 3) * 2304 + pix];
    }
    float acc = (a0 + a1p) + (a2p + a3p);

    int co = o >> 2, ry = (o >> 1) & 1, rx = o & 1;
    out[((co * 96 + 2 * y + ry) * 96) + 2 * x + rx] = acc;
}

extern "C" void kernel_launch(void* const* d_in, const int* in_sizes, int n_in,
                              void* d_out, int out_size, void* d_ws, size_t ws_size,
                              hipStream_t stream)
{
    const float* feats_l1 = (const float*)d_in[0];
    const float* feats_l2 = (const float*)d_in[1];
    const float* feats_l3 = (const float*)d_in[2];
    const float* agg_l3_w = (const float*)d_in[3];
    const float* agg_l3_b = (const float*)d_in[4];
    const float* wp_l3_w  = (const float*)d_in[5];
    const float* wp_l3_b  = (const float*)d_in[6];
    const float* agg_l2_w = (const float*)d_in[7];
    const float* agg_l2_b = (const float*)d_in[8];
    const float* wp_l2_w  = (const float*)d_in[9];
    const float* wp_l2_b  = (const float*)d_in[10];
    const float* agg_l1_w = (const float*)d_in[11];
    const float* agg_l1_b = (const float*)d_in[12];
    const float* wp_l1_w  = (const float*)d_in[13];
    const float* wp_l1_b  = (const float*)d_in[14];
    const float* up_w     = (const float*)d_in[15];
    const float* up_b     = (const float*)d_in[16];
    float* out = (float*)d_out;

    float* ws   = (float*)d_ws;
    float* agg3 = ws;                  // 3*32*12*12  = 13824
    float* a3up = agg3 + 13824;        // 3*32*24*24  = 55296
    float* agg2 = a3up + 55296;        // 3*32*24*24  = 55296
    float* a2up = agg2 + 55296;        // 3*32*48*48  = 221184
    float* a1   = a2up + 221184;       // 3*32*48*48  = 221184

    // level 3 (12x12, d=3), 1x1 tiles -> 144 x 3 = 432 blocks, no add
    agg_tile<3, 1, 12, 12, false><<<dim3(144, 3), 256, 0, stream>>>(
        feats_l3, nullptr, agg_l3_w, agg_l3_b, wp_l3_w, wp_l3_b, agg3);
    up2_kernel<<<(96 * 24 * 24 + 255) / 256, 256, 0, stream>>>(agg3, a3up, 96, 12, 12);

    // level 2 (24x24, d=5), 2x2 tiles -> 144 x 3 = 432 blocks
    agg_tile<5, 2, 24, 24, true><<<dim3(144, 3), 256, 0, stream>>>(
        feats_l2, a3up, agg_l2_w, agg_l2_b, wp_l2_w, wp_l2_b, agg2);
    up2_kernel<<<(96 * 48 * 48 + 255) / 256, 256, 0, stream>>>(agg2, a2up, 96, 24, 24);

    // level 1 (48x48, d=7), 3x3 tiles -> 256 x 3 = 768 blocks (= 3/CU)
    agg_tile<7, 3, 48, 48, true><<<dim3(256, 3), 256, 0, stream>>>(
        feats_l1, a2up, agg_l1_w, agg_l1_b, wp_l1_w, wp_l1_b, a1);

    // final projection + pixel shuffle (o uniform per block -> scalar weights)
    final_kernel<<<dim3(9, 128), 256, 0, stream>>>(a1, up_w, up_b, out);
}